// Round 10
// baseline (237.403 us; speedup 1.0000x reference)
//
#include <hip/hip_runtime.h>
#include <hip/hip_bf16.h>
#include <hip/hip_cooperative_groups.h>

namespace cg = cooperative_groups;

#define NV 40962
#define NK 9
#define CIN 32
#define COUT 32
#define NT 2561                // v-tiles of 16 in conv phase
#define NCHUNK 641             // 64-vertex transpose chunks
#define MAXBLK 1024            // cap: 4 blocks/CU
#define NV81 (NV * 81)
#define NV9  (NV * 9)

typedef __attribute__((ext_vector_type(8))) short bf16x8;
typedef __attribute__((ext_vector_type(4))) float f32x4;
typedef __attribute__((ext_vector_type(2))) float f32x2;

// ---- packed f32 FMA/MUL, src0 broadcast from pair half (VOP3P op_sel)
#define PKFMA_L(A, G, R) asm("v_pk_fma_f32 %0, %1, %2, %0 op_sel:[0,0,0] op_sel_hi:[0,1,1]" : "+v"(A) : "v"(G), "v"(R))
#define PKFMA_H(A, G, R) asm("v_pk_fma_f32 %0, %1, %2, %0 op_sel:[1,0,0] op_sel_hi:[1,1,1]" : "+v"(A) : "v"(G), "v"(R))
#define PKMUL_L(A, G, R) asm("v_pk_mul_f32 %0, %1, %2 op_sel:[0,0] op_sel_hi:[0,1]" : "=v"(A) : "v"(G), "v"(R))
#define PKMUL_H(A, G, R) asm("v_pk_mul_f32 %0, %1, %2 op_sel:[1,0] op_sel_hi:[1,1]" : "=v"(A) : "v"(G), "v"(R))

#define ACC(cc, j) ((j) == 8 ? acc8[cc] : (((j) & 1) ? acc2[cc][(j) >> 1].y \
                                                     : acc2[cc][(j) >> 1].x))

// f32 pair -> packed bf16 dword (a=low), via v_cvt_pk_bf16_f32 (RNE)
__device__ __forceinline__ unsigned pkbf(float a, float b) {
    union { __hip_bfloat162 h2; unsigned u; } cv;
    cv.h2 = __float22bfloat162_rn(make_float2(a, b));
    return cv.u;
}

// ===========================================================================
// FUSED cooperative kernel: phase 1 transpose+convert, grid sync, phase 2
// conv (verbatim R4 body, grid-strided -> persistent residency).
// LDS: one 16640B buffer, aliased (phase1: U[64][65] dwords;
// phase2: per-wave itp slices, 4 x 432 floats).
// ===========================================================================
__global__ void __launch_bounds__(256, 2) fused_sparse_conv(
    const float* __restrict__ x, const int* __restrict__ index,
    const float* __restrict__ itp, const float* __restrict__ w,
    const float* __restrict__ bias, unsigned* __restrict__ xtw,
    unsigned short* __restrict__ wbf, float* __restrict__ out)
{
    __shared__ unsigned shbuf[64 * 65];            // 16640 B, aliased

    const int t = threadIdx.x;

    // ---------------- phase 1a: weight convert (grid-strided) -------------
    for (int ci = blockIdx.x * 256 + t; ci < COUT * CIN * NK;
         ci += gridDim.x * 256) {
        const int o = ci / 288;
        const int r = ci - o * 288;
        const int c = r / 9;
        const int j = r - c * 9;
        unsigned u = __float_as_uint(w[ci]);
        wbf[o * 288 + j * 32 + c] =
            (unsigned short)((u + 0x7FFFu + ((u >> 16) & 1u)) >> 16);
    }

    // ---------------- phase 1b: transpose chunks (grid-strided) -----------
    // x [128 rows=(b*32+c)][V] f32 -> xt [v][coct(4)][b(4)][8ch] bf16
    for (int chunk = blockIdx.x; chunk < NCHUNK; chunk += gridDim.x) {
        __syncthreads();                           // U safe from prev readers
        const int v0  = chunk * 64;
        const int l16 = t & 15;
        const int p   = t >> 4;
        #pragma unroll
        for (int i = 0; i < 4; ++i) {
            const int q   = p * 4 + i;             // row-pair 0..63
            const int r0  = 2 * q;
            const int bb  = r0 >> 5;
            const int c0  = r0 & 31;
            const int dwb = (c0 >> 3) * 16 + bb * 4 + ((c0 & 7) >> 1);
            const float* rowA = x + (size_t)r0 * NV + v0;
            const float* rowB = rowA + NV;
            #pragma unroll
            for (int hv = 0; hv < 2; ++hv) {
                const int v = l16 * 2 + hv * 32;   // even pair (v, v+1)
                float2 a = make_float2(0.f, 0.f), c2 = make_float2(0.f, 0.f);
                if (v0 + v < NV) {                 // NV even: no cross
                    a  = *(const float2*)(rowA + v);
                    c2 = *(const float2*)(rowB + v);
                }
                shbuf[(v    ) * 65 + dwb] = pkbf(a.x, c2.x);
                shbuf[(v + 1) * 65 + dwb] = pkbf(a.y, c2.y);
            }
        }
        __syncthreads();
        const int v  = t >> 2;
        const int qo = t & 3;
        if (v0 + v < NV) {
            #pragma unroll
            for (int j = 0; j < 4; ++j) {
                const int n = j * 4 + qo;          // 16B chunk id
                uint4 d;
                d.x = shbuf[v * 65 + n * 4 + 0];
                d.y = shbuf[v * 65 + n * 4 + 1];
                d.z = shbuf[v * 65 + n * 4 + 2];
                d.w = shbuf[v * 65 + n * 4 + 3];
                *(uint4*)&xtw[(size_t)(v0 + v) * 64 + n * 4] = d;
            }
        }
    }

    // ---------------- grid barrier (device-scope fences for XCD L2) -------
    __threadfence();
    cg::this_grid().sync();
    __threadfence();

    // ---------------- phase 2: conv (verbatim R4 body, grid-strided) ------
    const unsigned short* xt = (const unsigned short*)xtw;
    const int w_    = t >> 6;
    const int lane  = t & 63;
    const int arow  = lane & 15;
    const int coct  = lane >> 4;
    const int b     = (lane >> 2) & 3;
    const int vv    = lane & 3;
    float* itp_w    = ((float*)shbuf) + w_ * 432;  // per-wave slice

    float bs0[4], bs1[4];
    #pragma unroll
    for (int r = 0; r < 4; ++r) {
        bs0[r] = bias[coct * 4 + r];
        bs1[r] = bias[coct * 4 + 16 + r];
    }
    const unsigned short* gbase = xt + coct * 32 + b * 8;
    const int lidx = (lane < 36) ? lane : 35;

    for (int tile = blockIdx.x; tile < NT; tile += gridDim.x) {
        // 1. idx load (lanes 0..35 carry the wave's 36 neighbor ids)
        int ia = tile * 144 + w_ * 36 + lidx;
        ia = ia < NV9 ? ia : NV9 - 1;
        const int myidx = index[ia];

        // 2. itp loads -> regs (contiguous, 324 floats per wave)
        float iv[6];
        const size_t ibase = (size_t)(tile * 16 + w_ * 4) * 81;
        #pragma unroll
        for (int i = 0; i < 6; ++i) {
            const int o = i * 64 + lane;
            iv[i] = (o < 324 && ibase + o < (size_t)NV81) ? itp[ibase + o]
                                                          : 0.0f;
        }

        // 3. weight loads -> regs (18 x dwordx4 from L2-hot wbf)
        const unsigned short* wb0 = wbf + arow * 288 + coct * 8;
        uint4 wa0[NK], wa1[NK];
        #pragma unroll
        for (int ks = 0; ks < NK; ++ks) {
            wa0[ks] = *(const uint4*)(wb0 + ks * 32);
            wa1[ks] = *(const uint4*)(wb0 + 16 * 288 + ks * 32);
        }

        // 4. neighbor ids via shfl, issue all 9 dense gathers
        int nbr[NK];
        #pragma unroll
        for (int n = 0; n < NK; ++n) nbr[n] = __shfl(myidx, vv * 9 + n);
        uint4 g[NK];
        #pragma unroll
        for (int n = 0; n < NK; ++n)
            g[n] = *(const uint4*)(gbase + (size_t)nbr[n] * 128);

        // 5. scatter itp into this wave's LDS slice (wave-synchronous)
        __builtin_amdgcn_wave_barrier();           // prev reads before writes
        #pragma unroll
        for (int i = 0; i < 6; ++i) {
            const int o = i * 64 + lane;
            if (o < 324) {
                const int vloc = o / 81;
                const int r2   = o - vloc * 81;
                const int kk   = r2 / 9;
                const int jj   = r2 - kk * 9;
                itp_w[vloc * 108 + kk * 12 + jj] = iv[i];
            }
        }
        __builtin_amdgcn_wave_barrier();           // writes before reads

        // 6. interp + frag pack
        unsigned frag[9][4];
        unsigned nzbits = 0;
        #pragma unroll
        for (int n = 0; n < NK; ++n)
            nzbits |= (g[n].x | g[n].y | g[n].z | g[n].w);
        nzbits &= 0x7FFF7FFFu;

        const float* ib = itp_w + vv * 108;
        #pragma unroll
        for (int h = 0; h < 2; ++h) {              // 4 channels per half
            f32x2 acc2[4][4];
            float acc8[4];
            #pragma unroll
            for (int n = 0; n < NK; ++n) {
                const uint2 gk = h ? make_uint2(g[n].z, g[n].w)
                                   : make_uint2(g[n].x, g[n].y);
                f32x2 gp01, gp23;
                gp01.x = __uint_as_float(gk.x << 16);
                gp01.y = __uint_as_float(gk.x & 0xFFFF0000u);
                gp23.x = __uint_as_float(gk.y << 16);
                gp23.y = __uint_as_float(gk.y & 0xFFFF0000u);
                const float* ir = ib + n * 12;
                const f32x4 ra = *(const f32x4*)ir;
                const f32x4 rb = *(const f32x4*)(ir + 4);
                const float r8 = ir[8];
                f32x2 rp[4];
                rp[0] = __builtin_shufflevector(ra, ra, 0, 1);
                rp[1] = __builtin_shufflevector(ra, ra, 2, 3);
                rp[2] = __builtin_shufflevector(rb, rb, 0, 1);
                rp[3] = __builtin_shufflevector(rb, rb, 2, 3);
                if (n == 0) {
                    #pragma unroll
                    for (int jp = 0; jp < 4; ++jp) {
                        PKMUL_L(acc2[0][jp], gp01, rp[jp]);
                        PKMUL_H(acc2[1][jp], gp01, rp[jp]);
                        PKMUL_L(acc2[2][jp], gp23, rp[jp]);
                        PKMUL_H(acc2[3][jp], gp23, rp[jp]);
                    }
                    acc8[0] = gp01.x * r8; acc8[1] = gp01.y * r8;
                    acc8[2] = gp23.x * r8; acc8[3] = gp23.y * r8;
                } else {
                    #pragma unroll
                    for (int jp = 0; jp < 4; ++jp) {
                        PKFMA_L(acc2[0][jp], gp01, rp[jp]);
                        PKFMA_H(acc2[1][jp], gp01, rp[jp]);
                        PKFMA_L(acc2[2][jp], gp23, rp[jp]);
                        PKFMA_H(acc2[3][jp], gp23, rp[jp]);
                    }
                    acc8[0] += gp01.x * r8; acc8[1] += gp01.y * r8;
                    acc8[2] += gp23.x * r8; acc8[3] += gp23.y * r8;
                }
            }
            #pragma unroll
            for (int ks = 0; ks < 9; ++ks) {
                frag[ks][2 * h]     = pkbf(ACC(0, ks), ACC(1, ks));
                frag[ks][2 * h + 1] = pkbf(ACC(2, ks), ACC(3, ks));
            }
        }

        // nz over all 32 channels of this lane's (b, vv) column
        unsigned nzw = nzbits;
        nzw |= __shfl_xor(nzw, 16);
        nzw |= __shfl_xor(nzw, 32);

        // 7. MFMA: 9 K'-steps x 2 o-halves; A-operand from registers
        f32x4 c0 = {0.f, 0.f, 0.f, 0.f};
        f32x4 c1 = {0.f, 0.f, 0.f, 0.f};
        #pragma unroll
        for (int ks = 0; ks < 9; ++ks) {
            union { uint4 u; bf16x8 v; } bfr, au0, au1;
            bfr.u.x = frag[ks][0]; bfr.u.y = frag[ks][1];
            bfr.u.z = frag[ks][2]; bfr.u.w = frag[ks][3];
            au0.u = wa0[ks];
            au1.u = wa1[ks];
            c0 = __builtin_amdgcn_mfma_f32_16x16x32_bf16(au0.v, bfr.v, c0, 0, 0, 0);
            c1 = __builtin_amdgcn_mfma_f32_16x16x32_bf16(au1.v, bfr.v, c1, 0, 0, 0);
        }

        // 8. epilogue
        const int vglob = tile * 16 + w_ * 4 + vv;
        if (vglob < NV) {
            const float m = nzw ? 1.0f : 0.0f;
            float* ob = out + (size_t)b * (COUT * NV) + vglob;
            #pragma unroll
            for (int r = 0; r < 4; ++r) {
                ob[(size_t)(coct * 4 + r) * NV]      = (c0[r] + bs0[r]) * m;
                ob[(size_t)(coct * 4 + 16 + r) * NV] = (c1[r] + bs1[r]) * m;
            }
        }
    }
}

// ===========================================================================
// FALLBACK path: the proven R4 two-kernel pipeline (used only if cooperative
// launch is unavailable). Verbatim from R4 (124.15 us verified).
// ===========================================================================
__global__ void __launch_bounds__(256) transpose_x_bf16(
    const float* __restrict__ x, unsigned* __restrict__ xtw,
    const float* __restrict__ w, unsigned short* __restrict__ wbf)
{
    __shared__ unsigned U[64 * 65];
    const int t = threadIdx.x;

    const int ci = blockIdx.x * 256 + t;
    if (ci < COUT * CIN * NK) {
        const int o = ci / 288;
        const int r = ci - o * 288;
        const int c = r / 9;
        const int j = r - c * 9;
        unsigned u = __float_as_uint(w[ci]);
        wbf[o * 288 + j * 32 + c] =
            (unsigned short)((u + 0x7FFFu + ((u >> 16) & 1u)) >> 16);
    }

    const int v0  = blockIdx.x * 64;
    const int l16 = t & 15;
    const int p   = t >> 4;

    #pragma unroll
    for (int i = 0; i < 4; ++i) {
        const int q   = p * 4 + i;
        const int r0  = 2 * q;
        const int bb  = r0 >> 5;
        const int c0  = r0 & 31;
        const int dwb = (c0 >> 3) * 16 + bb * 4 + ((c0 & 7) >> 1);
        const float* rowA = x + (size_t)r0 * NV + v0;
        const float* rowB = rowA + NV;
        #pragma unroll
        for (int hv = 0; hv < 2; ++hv) {
            const int v = l16 * 2 + hv * 32;
            float2 a = make_float2(0.f, 0.f), c2 = make_float2(0.f, 0.f);
            if (v0 + v < NV) {
                a  = *(const float2*)(rowA + v);
                c2 = *(const float2*)(rowB + v);
            }
            U[(v    ) * 65 + dwb] = pkbf(a.x, c2.x);
            U[(v + 1) * 65 + dwb] = pkbf(a.y, c2.y);
        }
    }
    __syncthreads();

    const int v  = t >> 2;
    const int qo = t & 3;
    if (v0 + v < NV) {
        #pragma unroll
        for (int j = 0; j < 4; ++j) {
            const int n = j * 4 + qo;
            uint4 d;
            d.x = U[v * 65 + n * 4 + 0];
            d.y = U[v * 65 + n * 4 + 1];
            d.z = U[v * 65 + n * 4 + 2];
            d.w = U[v * 65 + n * 4 + 3];
            *(uint4*)&xtw[(size_t)(v0 + v) * 64 + n * 4] = d;
        }
    }
}

__global__ void __launch_bounds__(256, 2) sparse_conv_mfma(
    const unsigned short* __restrict__ xt, const int* __restrict__ index,
    const float* __restrict__ itp, const unsigned short* __restrict__ wbf,
    const float* __restrict__ bias, float* __restrict__ out)
{
    __shared__ float itp_s[4][4][108];

    const int t    = threadIdx.x;
    const int w    = t >> 6;
    const int lane = t & 63;
    const int arow = lane & 15;
    const int coct = lane >> 4;
    const int b    = (lane >> 2) & 3;
    const int vv   = lane & 3;
    const int tile = blockIdx.x;

    int ia = tile * 144 + w * 36 + (lane < 36 ? lane : 35);
    ia = ia < NV9 ? ia : NV9 - 1;
    const int myidx = index[ia];

    float iv[6];
    const size_t ibase = (size_t)(tile * 16 + w * 4) * 81;
    #pragma unroll
    for (int i = 0; i < 6; ++i) {
        const int o = i * 64 + lane;
        iv[i] = (o < 324 && ibase + o < (size_t)NV81) ? itp[ibase + o] : 0.0f;
    }

    const unsigned short* wb0 = wbf + arow * 288 + coct * 8;
    uint4 wa0[NK], wa1[NK];
    #pragma unroll
    for (int ks = 0; ks < NK; ++ks) {
        wa0[ks] = *(const uint4*)(wb0 + ks * 32);
        wa1[ks] = *(const uint4*)(wb0 + 16 * 288 + ks * 32);
    }

    float bs0[4], bs1[4];
    #pragma unroll
    for (int r = 0; r < 4; ++r) {
        bs0[r] = bias[coct * 4 + r];
        bs1[r] = bias[coct * 4 + 16 + r];
    }

    int nbr[NK];
    #pragma unroll
    for (int n = 0; n < NK; ++n) nbr[n] = __shfl(myidx, vv * 9 + n);
    const unsigned short* gbase = xt + coct * 32 + b * 8;
    uint4 g[NK];
    #pragma unroll
    for (int n = 0; n < NK; ++n)
        g[n] = *(const uint4*)(gbase + (size_t)nbr[n] * 128);

    #pragma unroll
    for (int i = 0; i < 6; ++i) {
        const int o = i * 64 + lane;
        if (o < 324) {
            const int vloc = o / 81;
            const int r2   = o - vloc * 81;
            const int kk   = r2 / 9;
            const int jj   = r2 - kk * 9;
            itp_s[w][vloc][kk * 12 + jj] = iv[i];
        }
    }
    __builtin_amdgcn_wave_barrier();

    unsigned frag[9][4];
    unsigned nzbits = 0;
    #pragma unroll
    for (int n = 0; n < NK; ++n)
        nzbits |= (g[n].x | g[n].y | g[n].z | g[n].w);
    nzbits &= 0x7FFF7FFFu;

    const float* ib = &itp_s[w][vv][0];
    #pragma unroll
    for (int h = 0; h < 2; ++h) {
        f32x2 acc2[4][4];
        float acc8[4];
        #pragma unroll
        for (int n = 0; n < NK; ++n) {
            const uint2 gk = h ? make_uint2(g[n].z, g[n].w)
                               : make_uint2(g[n].x, g[n].y);
            f32x2 gp01, gp23;
            gp01.x = __uint_as_float(gk.x << 16);
            gp01.y = __uint_as_float(gk.x & 0xFFFF0000u);
            gp23.x = __uint_as_float(gk.y << 16);
            gp23.y = __uint_as_float(gk.y & 0xFFFF0000u);
            const float* ir = ib + n * 12;
            const f32x4 ra = *(const f32x4*)ir;
            const f32x4 rb = *(const f32x4*)(ir + 4);
            const float r8 = ir[8];
            f32x2 rp[4];
            rp[0] = __builtin_shufflevector(ra, ra, 0, 1);
            rp[1] = __builtin_shufflevector(ra, ra, 2, 3);
            rp[2] = __builtin_shufflevector(rb, rb, 0, 1);
            rp[3] = __builtin_shufflevector(rb, rb, 2, 3);
            if (n == 0) {
                #pragma unroll
                for (int jp = 0; jp < 4; ++jp) {
                    PKMUL_L(acc2[0][jp], gp01, rp[jp]);
                    PKMUL_H(acc2[1][jp], gp01, rp[jp]);
                    PKMUL_L(acc2[2][jp], gp23, rp[jp]);
                    PKMUL_H(acc2[3][jp], gp23, rp[jp]);
                }
                acc8[0] = gp01.x * r8; acc8[1] = gp01.y * r8;
                acc8[2] = gp23.x * r8; acc8[3] = gp23.y * r8;
            } else {
                #pragma unroll
                for (int jp = 0; jp < 4; ++jp) {
                    PKFMA_L(acc2[0][jp], gp01, rp[jp]);
                    PKFMA_H(acc2[1][jp], gp01, rp[jp]);
                    PKFMA_L(acc2[2][jp], gp23, rp[jp]);
                    PKFMA_H(acc2[3][jp], gp23, rp[jp]);
                }
                acc8[0] += gp01.x * r8; acc8[1] += gp01.y * r8;
                acc8[2] += gp23.x * r8; acc8[3] += gp23.y * r8;
            }
        }
        #pragma unroll
        for (int ks = 0; ks < 9; ++ks) {
            frag[ks][2 * h]     = pkbf(ACC(0, ks), ACC(1, ks));
            frag[ks][2 * h + 1] = pkbf(ACC(2, ks), ACC(3, ks));
        }
    }

    unsigned nzw = nzbits;
    nzw |= __shfl_xor(nzw, 16);
    nzw |= __shfl_xor(nzw, 32);

    f32x4 c0 = {0.f, 0.f, 0.f, 0.f};
    f32x4 c1 = {0.f, 0.f, 0.f, 0.f};
    #pragma unroll
    for (int ks = 0; ks < 9; ++ks) {
        union { uint4 u; bf16x8 v; } bfr, au0, au1;
        bfr.u.x = frag[ks][0]; bfr.u.y = frag[ks][1];
        bfr.u.z = frag[ks][2]; bfr.u.w = frag[ks][3];
        au0.u = wa0[ks];
        au1.u = wa1[ks];
        c0 = __builtin_amdgcn_mfma_f32_16x16x32_bf16(au0.v, bfr.v, c0, 0, 0, 0);
        c1 = __builtin_amdgcn_mfma_f32_16x16x32_bf16(au1.v, bfr.v, c1, 0, 0, 0);
    }

    const int vglob = tile * 16 + w * 4 + vv;
    if (vglob < NV) {
        const float m = nzw ? 1.0f : 0.0f;
        float* ob = out + (size_t)b * (COUT * NV) + vglob;
        #pragma unroll
        for (int r = 0; r < 4; ++r) {
            ob[(size_t)(coct * 4 + r) * NV]      = (c0[r] + bs0[r]) * m;
            ob[(size_t)(coct * 4 + 16 + r) * NV] = (c1[r] + bs1[r]) * m;
        }
    }
}

// ---------------------------------------------------------------------------
extern "C" void kernel_launch(void* const* d_in, const int* in_sizes, int n_in,
                              void* d_out, int out_size, void* d_ws, size_t ws_size,
                              hipStream_t stream)
{
    const float* x     = (const float*)d_in[0];
    const int*   index = (const int*)  d_in[1];
    const float* itp   = (const float*)d_in[2];
    const float* w     = (const float*)d_in[3];
    const float* bias  = (const float*)d_in[4];
    float*       out   = (float*)d_out;

    unsigned short* xt  = (unsigned short*)d_ws;                 // 10.5 MB
    unsigned short* wbf = (unsigned short*)((char*)d_ws + (size_t)NV * 256);
    unsigned*       xtw = (unsigned*)xt;

    // cooperative path: one fused kernel, grid <= co-resident capacity
    int coop = 0;
    hipDeviceGetAttribute(&coop, hipDeviceAttributeCooperativeLaunch, 0);
    int nb = 0;
    hipOccupancyMaxActiveBlocksPerMultiprocessor(&nb, fused_sparse_conv, 256, 0);
    int grid = nb * 256;
    if (grid > MAXBLK) grid = MAXBLK;

    bool launched = false;
    if (coop && grid >= 256) {
        void* args[8] = { (void*)&x, (void*)&index, (void*)&itp, (void*)&w,
                          (void*)&bias, (void*)&xtw, (void*)&wbf, (void*)&out };
        hipError_t e = hipLaunchCooperativeKernel(fused_sparse_conv,
                                                  dim3(grid), dim3(256),
                                                  args, 0, stream);
        launched = (e == hipSuccess);
    }

    if (!launched) {
        // proven R4 two-kernel fallback
        hipLaunchKernelGGL(transpose_x_bf16, dim3(NCHUNK), dim3(256), 0,
                           stream, x, xtw, w, wbf);
        hipLaunchKernelGGL(sparse_conv_mfma, dim3(NT), dim3(256), 0,
                           stream, xt, index, itp, wbf, bias, out);
    }
}

// Round 11
// 127.778 us; speedup vs baseline: 1.8579x; 1.8579x over previous
//
#include <hip/hip_runtime.h>
#include <hip/hip_bf16.h>

#define NV 40962
#define NK 9
#define CIN 32
#define COUT 32
#define NT 2561                // v-tiles of 16
#define NB ((NT + 1) / 2)      // conv blocks: 2 tiles per 512-thr block
#define NV81 (NV * 81)
#define NV9  (NV * 9)

typedef __attribute__((ext_vector_type(8))) short bf16x8;
typedef __attribute__((ext_vector_type(4))) float f32x4;
typedef __attribute__((ext_vector_type(2))) float f32x2;

// ---- packed f32 FMA/MUL, src0 broadcast from pair half (VOP3P op_sel)
#define PKFMA_L(A, G, R) asm("v_pk_fma_f32 %0, %1, %2, %0 op_sel:[0,0,0] op_sel_hi:[0,1,1]" : "+v"(A) : "v"(G), "v"(R))
#define PKFMA_H(A, G, R) asm("v_pk_fma_f32 %0, %1, %2, %0 op_sel:[1,0,0] op_sel_hi:[1,1,1]" : "+v"(A) : "v"(G), "v"(R))
#define PKMUL_L(A, G, R) asm("v_pk_mul_f32 %0, %1, %2 op_sel:[0,0] op_sel_hi:[0,1]" : "=v"(A) : "v"(G), "v"(R))
#define PKMUL_H(A, G, R) asm("v_pk_mul_f32 %0, %1, %2 op_sel:[1,0] op_sel_hi:[1,1]" : "=v"(A) : "v"(G), "v"(R))

#define ACC(cc, j) ((j) == 8 ? acc8[cc] : (((j) & 1) ? acc2[cc][(j) >> 1].y \
                                                     : acc2[cc][(j) >> 1].x))

// f32 pair -> packed bf16 dword (a=low), via v_cvt_pk_bf16_f32 (RNE)
__device__ __forceinline__ unsigned pkbf(float a, float b) {
    union { __hip_bfloat162 h2; unsigned u; } cv;
    cv.h2 = __float22bfloat162_rn(make_float2(a, b));
    return cv.u;
}

// ---------------------------------------------------------------------------
// Kernel 1: transpose + weight-convert fused (VERBATIM R4 — proven).
// x [128 rows=(b*32+c)][V] f32 -> xt [v][coct(4)][b(4)][8ch] bf16.
// Blocks 0..35 also do the conv-weight f32->bf16 K-permute.
// ---------------------------------------------------------------------------
__global__ void __launch_bounds__(256) transpose_x_bf16(
    const float* __restrict__ x, unsigned* __restrict__ xtw,
    const float* __restrict__ w, unsigned short* __restrict__ wbf)
{
    __shared__ unsigned U[64 * 65];          // [v][64 dw + 1 pad], 16640 B
    const int t = threadIdx.x;

    // merged convert_w: wbf[o][k' = j*32 + c]
    const int ci = blockIdx.x * 256 + t;
    if (ci < COUT * CIN * NK) {
        const int o = ci / 288;
        const int r = ci - o * 288;
        const int c = r / 9;
        const int j = r - c * 9;
        unsigned u = __float_as_uint(w[ci]);
        wbf[o * 288 + j * 32 + c] =
            (unsigned short)((u + 0x7FFFu + ((u >> 16) & 1u)) >> 16);
    }

    const int v0  = blockIdx.x * 64;
    const int l16 = t & 15;
    const int p   = t >> 4;                  // row-pair group 0..15

    #pragma unroll
    for (int i = 0; i < 4; ++i) {
        const int q    = p * 4 + i;          // row-pair 0..63
        const int r0   = 2 * q;              // even row; r0+1 same batch
        const int bb   = r0 >> 5;
        const int c0   = r0 & 31;            // even channel
        const int dwb  = (c0 >> 3) * 16 + bb * 4 + ((c0 & 7) >> 1);
        const float* rowA = x + (size_t)r0 * NV + v0;
        const float* rowB = rowA + NV;
        #pragma unroll
        for (int hv = 0; hv < 2; ++hv) {
            const int v = l16 * 2 + hv * 32; // even, pair (v, v+1)
            float2 a = make_float2(0.f, 0.f), c2 = make_float2(0.f, 0.f);
            if (v0 + v < NV) {               // NV even: pair never crosses
                a  = *(const float2*)(rowA + v);
                c2 = *(const float2*)(rowB + v);
            }
            U[(v    ) * 65 + dwb] = pkbf(a.x, c2.x);
            U[(v + 1) * 65 + dwb] = pkbf(a.y, c2.y);
        }
    }
    __syncthreads();

    // write out: full 64B sectors (lanes qo=0..3 cover one sector)
    const int v  = t >> 2;
    const int qo = t & 3;
    if (v0 + v < NV) {
        #pragma unroll
        for (int j = 0; j < 4; ++j) {
            const int n = j * 4 + qo;        // 16B chunk id 0..15
            uint4 d;
            d.x = U[v * 65 + n * 4 + 0];
            d.y = U[v * 65 + n * 4 + 1];
            d.z = U[v * 65 + n * 4 + 2];
            d.w = U[v * 65 + n * 4 + 3];
            *(uint4*)&xtw[(size_t)(v0 + v) * 64 + n * 4] = d;
        }
    }
}

// ---------------------------------------------------------------------------
// Kernel 2: R4 conv body, 512-thr blocks (8 waves = 2 tiles in parallel).
// Wave w serves tile blockIdx*2 + (w>>2) with role wv = w&3; the per-wave
// code, lane mapping, memory layout, and register footprint are IDENTICAL
// to R4's proven 124-VGPR kernel. Grid halves (2561 -> 1281) and each
// dispatch carries 2x the waves -> tests whether block feed-rate /
// per-block start latency capped R4's concurrency (~1.4 blocks/CU).
// NO __syncthreads; waves fully autonomous.
// Lane: coct = l>>4 (k-octet), b = (l>>2)&3, vv = l&3, arow = l&15.
// ---------------------------------------------------------------------------
__global__ void __launch_bounds__(512, 2) sparse_conv_mfma(
    const unsigned short* __restrict__ xt, const int* __restrict__ index,
    const float* __restrict__ itp, const unsigned short* __restrict__ wbf,
    const float* __restrict__ bias, float* __restrict__ out)
{
    __shared__ float itp_s[8][4][108];       // per-wave slice, 13824 B

    const int t    = threadIdx.x;
    const int w    = t >> 6;                 // physical wave 0..7
    const int wv   = w & 3;                  // wave-within-tile (R4's w)
    const int tile = blockIdx.x * 2 + (w >> 2);
    const int lane = t & 63;
    const int arow = lane & 15;
    const int coct = lane >> 4;
    const int b    = (lane >> 2) & 3;
    const int vv   = lane & 3;

    // 1. idx load (lanes 0..35 carry the wave's 36 neighbor ids)
    int ia = tile * 144 + wv * 36 + (lane < 36 ? lane : 35);
    ia = ia < NV9 ? ia : NV9 - 1;            // tail clamp: any valid id safe
    const int myidx = index[ia];

    // 2. itp loads -> regs (contiguous, 324 floats per wave)
    float iv[6];
    const size_t ibase = (size_t)(tile * 16 + wv * 4) * 81;
    #pragma unroll
    for (int i = 0; i < 6; ++i) {
        const int o = i * 64 + lane;
        iv[i] = (o < 324 && ibase + o < (size_t)NV81) ? itp[ibase + o] : 0.0f;
    }

    // 3. weight loads -> regs (18 x dwordx4 from L2-hot wbf)
    const unsigned short* wb0 = wbf + arow * 288 + coct * 8;
    uint4 wa0[NK], wa1[NK];
    #pragma unroll
    for (int ks = 0; ks < NK; ++ks) {
        wa0[ks] = *(const uint4*)(wb0 + ks * 32);
        wa1[ks] = *(const uint4*)(wb0 + 16 * 288 + ks * 32);
    }

    // bias -> regs
    float bs0[4], bs1[4];
    #pragma unroll
    for (int r = 0; r < 4; ++r) {
        bs0[r] = bias[coct * 4 + r];
        bs1[r] = bias[coct * 4 + 16 + r];
    }

    // 4. neighbor ids via shfl, then issue all 9 dense gathers
    int nbr[NK];
    #pragma unroll
    for (int n = 0; n < NK; ++n) nbr[n] = __shfl(myidx, vv * 9 + n);
    const unsigned short* gbase = xt + coct * 32 + b * 8;
    uint4 g[NK];
    #pragma unroll
    for (int n = 0; n < NK; ++n)
        g[n] = *(const uint4*)(gbase + (size_t)nbr[n] * 128);

    // 5. scatter itp into this wave's own LDS slice (wave-synchronous)
    #pragma unroll
    for (int i = 0; i < 6; ++i) {
        const int o = i * 64 + lane;
        if (o < 324) {
            const int vloc = o / 81;
            const int r2   = o - vloc * 81;
            const int kk   = r2 / 9;
            const int jj   = r2 - kk * 9;
            itp_s[w][vloc][kk * 12 + jj] = iv[i];
        }
    }
    __builtin_amdgcn_wave_barrier();         // pin write->read order

    // 6. interp + frag pack
    unsigned frag[9][4];
    unsigned nzbits = 0;
    #pragma unroll
    for (int n = 0; n < NK; ++n)
        nzbits |= (g[n].x | g[n].y | g[n].z | g[n].w);
    nzbits &= 0x7FFF7FFFu;

    const float* ib = &itp_s[w][vv][0];
    #pragma unroll
    for (int h = 0; h < 2; ++h) {            // 4 channels per half
        f32x2 acc2[4][4];
        float acc8[4];
        #pragma unroll
        for (int n = 0; n < NK; ++n) {
            const uint2 gk = h ? make_uint2(g[n].z, g[n].w)
                               : make_uint2(g[n].x, g[n].y);
            f32x2 gp01, gp23;
            gp01.x = __uint_as_float(gk.x << 16);
            gp01.y = __uint_as_float(gk.x & 0xFFFF0000u);
            gp23.x = __uint_as_float(gk.y << 16);
            gp23.y = __uint_as_float(gk.y & 0xFFFF0000u);
            const float* ir = ib + n * 12;
            const f32x4 ra = *(const f32x4*)ir;
            const f32x4 rb = *(const f32x4*)(ir + 4);
            const float r8 = ir[8];
            f32x2 rp[4];
            rp[0] = __builtin_shufflevector(ra, ra, 0, 1);
            rp[1] = __builtin_shufflevector(ra, ra, 2, 3);
            rp[2] = __builtin_shufflevector(rb, rb, 0, 1);
            rp[3] = __builtin_shufflevector(rb, rb, 2, 3);
            if (n == 0) {
                #pragma unroll
                for (int jp = 0; jp < 4; ++jp) {
                    PKMUL_L(acc2[0][jp], gp01, rp[jp]);
                    PKMUL_H(acc2[1][jp], gp01, rp[jp]);
                    PKMUL_L(acc2[2][jp], gp23, rp[jp]);
                    PKMUL_H(acc2[3][jp], gp23, rp[jp]);
                }
                acc8[0] = gp01.x * r8; acc8[1] = gp01.y * r8;
                acc8[2] = gp23.x * r8; acc8[3] = gp23.y * r8;
            } else {
                #pragma unroll
                for (int jp = 0; jp < 4; ++jp) {
                    PKFMA_L(acc2[0][jp], gp01, rp[jp]);
                    PKFMA_H(acc2[1][jp], gp01, rp[jp]);
                    PKFMA_L(acc2[2][jp], gp23, rp[jp]);
                    PKFMA_H(acc2[3][jp], gp23, rp[jp]);
                }
                acc8[0] += gp01.x * r8; acc8[1] += gp01.y * r8;
                acc8[2] += gp23.x * r8; acc8[3] += gp23.y * r8;
            }
        }
        #pragma unroll
        for (int ks = 0; ks < 9; ++ks) {
            frag[ks][2 * h]     = pkbf(ACC(0, ks), ACC(1, ks));
            frag[ks][2 * h + 1] = pkbf(ACC(2, ks), ACC(3, ks));
        }
    }

    // nz over all 32 channels of this lane's (b, vv) column
    unsigned nzw = nzbits;
    nzw |= __shfl_xor(nzw, 16);
    nzw |= __shfl_xor(nzw, 32);

    // 7. MFMA: 9 K'-steps x 2 o-halves; A-operand straight from registers
    f32x4 c0 = {0.f, 0.f, 0.f, 0.f};
    f32x4 c1 = {0.f, 0.f, 0.f, 0.f};
    #pragma unroll
    for (int ks = 0; ks < 9; ++ks) {
        union { uint4 u; bf16x8 v; } bfr, au0, au1;
        bfr.u.x = frag[ks][0]; bfr.u.y = frag[ks][1];
        bfr.u.z = frag[ks][2]; bfr.u.w = frag[ks][3];
        au0.u = wa0[ks];
        au1.u = wa1[ks];
        c0 = __builtin_amdgcn_mfma_f32_16x16x32_bf16(au0.v, bfr.v, c0, 0, 0, 0);
        c1 = __builtin_amdgcn_mfma_f32_16x16x32_bf16(au1.v, bfr.v, c1, 0, 0, 0);
    }

    // 8. epilogue: C col = arow = b*4+vv, row o = coct*4+r (+16)
    const int vglob = tile * 16 + wv * 4 + vv;
    if (vglob < NV) {
        const float m = nzw ? 1.0f : 0.0f;
        float* ob = out + (size_t)b * (COUT * NV) + vglob;
        #pragma unroll
        for (int r = 0; r < 4; ++r) {
            ob[(size_t)(coct * 4 + r) * NV]      = (c0[r] + bs0[r]) * m;
            ob[(size_t)(coct * 4 + 16 + r) * NV] = (c1[r] + bs1[r]) * m;
        }
    }
}

// ---------------------------------------------------------------------------
extern "C" void kernel_launch(void* const* d_in, const int* in_sizes, int n_in,
                              void* d_out, int out_size, void* d_ws, size_t ws_size,
                              hipStream_t stream)
{
    const float* x     = (const float*)d_in[0];
    const int*   index = (const int*)  d_in[1];
    const float* itp   = (const float*)d_in[2];
    const float* w     = (const float*)d_in[3];
    const float* bias  = (const float*)d_in[4];
    float*       out   = (float*)d_out;

    unsigned short* xt  = (unsigned short*)d_ws;                 // 10.5 MB
    unsigned short* wbf = (unsigned short*)((char*)d_ws + (size_t)NV * 256);

    const int vchunks = (NV + 63) / 64;      // 641 (>= 36 convert blocks)
    hipLaunchKernelGGL(transpose_x_bf16, dim3(vchunks), dim3(256), 0,
                       stream, x, (unsigned*)xt, w, wbf);
    hipLaunchKernelGGL(sparse_conv_mfma, dim3(NB), dim3(512), 0,
                       stream, xt, index, itp, wbf, bias, out);
}

// Round 12
// 125.137 us; speedup vs baseline: 1.8971x; 1.0211x over previous
//
#include <hip/hip_runtime.h>
#include <hip/hip_bf16.h>

#define NV 40962
#define NK 9
#define CIN 32
#define COUT 32
#define NTV 2561               // 16-vertex tiles per batch
#define NBPB 641               // conv blocks per batch (4 wave-tiles each)
#define NV81 (NV * 81)
#define NV9  (NV * 9)

typedef __attribute__((ext_vector_type(8))) short bf16x8;
typedef __attribute__((ext_vector_type(4))) float f32x4;
typedef __attribute__((ext_vector_type(2))) float f32x2;

// ---- packed f32 FMA/MUL, src0 broadcast from pair half (VOP3P op_sel)
#define PKFMA_L(A, G, R) asm("v_pk_fma_f32 %0, %1, %2, %0 op_sel:[0,0,0] op_sel_hi:[0,1,1]" : "+v"(A) : "v"(G), "v"(R))
#define PKFMA_H(A, G, R) asm("v_pk_fma_f32 %0, %1, %2, %0 op_sel:[1,0,0] op_sel_hi:[1,1,1]" : "+v"(A) : "v"(G), "v"(R))
#define PKMUL_L(A, G, R) asm("v_pk_mul_f32 %0, %1, %2 op_sel:[0,0] op_sel_hi:[0,1]" : "=v"(A) : "v"(G), "v"(R))
#define PKMUL_H(A, G, R) asm("v_pk_mul_f32 %0, %1, %2 op_sel:[1,0] op_sel_hi:[1,1]" : "=v"(A) : "v"(G), "v"(R))

#define ACC(cc, j) ((j) == 8 ? acc8[cc] : (((j) & 1) ? acc2[cc][(j) >> 1].y \
                                                     : acc2[cc][(j) >> 1].x))

// f32 pair -> packed bf16 dword (a=low), via v_cvt_pk_bf16_f32 (RNE)
__device__ __forceinline__ unsigned pkbf(float a, float b) {
    union { __hip_bfloat162 h2; unsigned u; } cv;
    cv.h2 = __float22bfloat162_rn(make_float2(a, b));
    return cv.u;
}

// ---------------------------------------------------------------------------
// Kernel 1: transpose + weight-convert fused.
// NEW layout: x [128 rows=(b*32+c)][V] f32 -> xt [b][v][32ch] bf16
// (64 B per (b,v) row). Per-batch slice = NV*64B = 2.62 MB -> fits a 4 MB
// XCD L2, enabling the conv's batch-phased L2-resident gathers.
// Blocks 0..35 also do the conv-weight f32->bf16 K-permute.
// ---------------------------------------------------------------------------
__global__ void __launch_bounds__(256) transpose_x_bf16(
    const float* __restrict__ x, unsigned* __restrict__ xtw,
    const float* __restrict__ w, unsigned short* __restrict__ wbf)
{
    __shared__ unsigned U[64 * 65];          // [v][64 dw + 1 pad], 16640 B
    const int t = threadIdx.x;

    // merged convert_w: wbf[o][k' = j*32 + c]
    const int ci = blockIdx.x * 256 + t;
    if (ci < COUT * CIN * NK) {
        const int o = ci / 288;
        const int r = ci - o * 288;
        const int c = r / 9;
        const int j = r - c * 9;
        unsigned u = __float_as_uint(w[ci]);
        wbf[o * 288 + j * 32 + c] =
            (unsigned short)((u + 0x7FFFu + ((u >> 16) & 1u)) >> 16);
    }

    const int v0  = blockIdx.x * 64;
    const int l16 = t & 15;
    const int p   = t >> 4;                  // row-pair group 0..15

    #pragma unroll
    for (int i = 0; i < 4; ++i) {
        const int q    = p * 4 + i;          // row-pair 0..63
        const int r0   = 2 * q;              // even row; r0+1 same batch
        const int bb   = r0 >> 5;
        const int c0   = r0 & 31;            // even channel
        const int dwb  = bb * 16 + (c0 >> 1);        // [b][ch-pair] dword
        const float* rowA = x + (size_t)r0 * NV + v0;
        const float* rowB = rowA + NV;
        #pragma unroll
        for (int hv = 0; hv < 2; ++hv) {
            const int v = l16 * 2 + hv * 32; // even, pair (v, v+1)
            float2 a = make_float2(0.f, 0.f), c2 = make_float2(0.f, 0.f);
            if (v0 + v < NV) {               // NV even: pair never crosses
                a  = *(const float2*)(rowA + v);
                c2 = *(const float2*)(rowB + v);
            }
            U[(v    ) * 65 + dwb] = pkbf(a.x, c2.x);
            U[(v + 1) * 65 + dwb] = pkbf(a.y, c2.y);
        }
    }
    __syncthreads();

    // write out: chunk n -> batch n>>2, 16B sub-chunk n&3 of the 64B row
    const int v  = t >> 2;
    const int qo = t & 3;
    if (v0 + v < NV) {
        #pragma unroll
        for (int j = 0; j < 4; ++j) {
            const int n = j * 4 + qo;        // 16B chunk id 0..15
            uint4 d;
            d.x = U[v * 65 + n * 4 + 0];
            d.y = U[v * 65 + n * 4 + 1];
            d.z = U[v * 65 + n * 4 + 2];
            d.w = U[v * 65 + n * 4 + 3];
            *(uint4*)&xtw[(size_t)(n >> 2) * (NV * 16)
                          + (size_t)(v0 + v) * 16 + (n & 3) * 4] = d;
        }
    }
}

// ---------------------------------------------------------------------------
// Kernel 2: BATCH-PHASED conv. Grid = 4 batches x NBPB blocks (batch-major
// order -> at any time all XCDs work on ONE batch; its 2.62 MB xt slice is
// L2-resident, turning the random gathers from ~900cy LLC hops into ~250cy
// L2 hits). Wave owns 16 vertices x 1 batch = the 16 MFMA columns.
// Lane: coct = l>>4 (k-octet, channels coct*8..+8), col = arow = l&15
// (vertex within tile). Per-lane interp/frag/MFMA code is VERBATIM R4
// (identical fragment semantics); only addressing/staging changed.
// idx (144 ids) and itp (1296 floats) staged via wave-local LDS slices,
// wave-synchronous only — NO __syncthreads anywhere.
// ---------------------------------------------------------------------------
__global__ void __launch_bounds__(256, 2) sparse_conv_mfma(
    const unsigned short* __restrict__ xt, const int* __restrict__ index,
    const float* __restrict__ itp, const unsigned short* __restrict__ wbf,
    const float* __restrict__ bias, float* __restrict__ out)
{
    __shared__ float itp_s[4][16 * 108];     // 27648 B, per-wave slice
    __shared__ int   idx_s[4][144];          //  2304 B, per-wave slice

    const int t    = threadIdx.x;
    const int w    = t >> 6;
    const int lane = t & 63;
    const int arow = lane & 15;              // MFMA column = vertex-in-tile
    const int coct = lane >> 4;              // channel octet = k-octet

    const int bq   = blockIdx.x / NBPB;      // batch phase 0..3
    const int vblk = blockIdx.x - bq * NBPB;
    const int vt   = vblk * 4 + w;           // wave's vertex tile
    if (vt >= NTV) return;                   // tail waves exit (no s_barrier)

    // 1. idx stage -> wave LDS slice (144 ids: 64+64+16)
    {
        const int ib0 = vt * 144;
        int ia0 = ib0 + lane;        ia0 = ia0 < NV9 ? ia0 : NV9 - 1;
        int ia1 = ib0 + 64 + lane;   ia1 = ia1 < NV9 ? ia1 : NV9 - 1;
        idx_s[w][lane]      = index[ia0];
        idx_s[w][64 + lane] = index[ia1];
        if (lane < 16) {
            int ia2 = ib0 + 128 + lane; ia2 = ia2 < NV9 ? ia2 : NV9 - 1;
            idx_s[w][128 + lane] = index[ia2];
        }
    }

    // 2. itp loads -> regs (contiguous, 1296 floats per wave, 21/lane)
    float iv[21];
    {
        const size_t tbase = (size_t)vt * 1296;
        #pragma unroll
        for (int i = 0; i < 21; ++i) {
            const int o = i * 64 + lane;
            iv[i] = (o < 1296 && tbase + o < (size_t)NV81) ? itp[tbase + o]
                                                           : 0.0f;
        }
    }

    // 3. weight loads -> regs (18 x dwordx4 from L2-hot wbf) — verbatim R4
    const unsigned short* wb0 = wbf + arow * 288 + coct * 8;
    uint4 wa0[NK], wa1[NK];
    #pragma unroll
    for (int ks = 0; ks < NK; ++ks) {
        wa0[ks] = *(const uint4*)(wb0 + ks * 32);
        wa1[ks] = *(const uint4*)(wb0 + 16 * 288 + ks * 32);
    }

    // bias -> regs
    float bs0[4], bs1[4];
    #pragma unroll
    for (int r = 0; r < 4; ++r) {
        bs0[r] = bias[coct * 4 + r];
        bs1[r] = bias[coct * 4 + 16 + r];
    }

    // 4. neighbor ids from wave LDS (4-way broadcast), then 9 dense gathers
    // from the L2-RESIDENT batch slice: addr = slice + nbr*64B + coct*16B
    __builtin_amdgcn_wave_barrier();         // idx writes before reads
    int nbr[NK];
    #pragma unroll
    for (int n = 0; n < NK; ++n) nbr[n] = idx_s[w][arow * 9 + n];
    const unsigned short* gbase = xt + (size_t)bq * (NV * 32) + coct * 8;
    uint4 g[NK];
    #pragma unroll
    for (int n = 0; n < NK; ++n)
        g[n] = *(const uint4*)(gbase + (size_t)nbr[n] * 32);

    // 5. scatter itp into this wave's LDS slice (wave-synchronous)
    #pragma unroll
    for (int i = 0; i < 21; ++i) {
        const int o = i * 64 + lane;
        if (o < 1296) {
            const int vloc = o / 81;
            const int r2   = o - vloc * 81;
            const int kk   = r2 / 9;
            const int jj   = r2 - kk * 9;
            itp_s[w][vloc * 108 + kk * 12 + jj] = iv[i];
        }
    }
    __builtin_amdgcn_wave_barrier();         // itp writes before reads

    // 6. interp + frag pack — verbatim R4 body (ib now indexed by col)
    unsigned frag[9][4];
    unsigned nzbits = 0;
    #pragma unroll
    for (int n = 0; n < NK; ++n)
        nzbits |= (g[n].x | g[n].y | g[n].z | g[n].w);
    nzbits &= 0x7FFF7FFFu;

    const float* ib = &itp_s[w][arow * 108];
    #pragma unroll
    for (int h = 0; h < 2; ++h) {            // 4 channels per half
        f32x2 acc2[4][4];
        float acc8[4];
        #pragma unroll
        for (int n = 0; n < NK; ++n) {
            const uint2 gk = h ? make_uint2(g[n].z, g[n].w)
                               : make_uint2(g[n].x, g[n].y);
            f32x2 gp01, gp23;
            gp01.x = __uint_as_float(gk.x << 16);
            gp01.y = __uint_as_float(gk.x & 0xFFFF0000u);
            gp23.x = __uint_as_float(gk.y << 16);
            gp23.y = __uint_as_float(gk.y & 0xFFFF0000u);
            const float* ir = ib + n * 12;
            const f32x4 ra = *(const f32x4*)ir;
            const f32x4 rb = *(const f32x4*)(ir + 4);
            const float r8 = ir[8];
            f32x2 rp[4];
            rp[0] = __builtin_shufflevector(ra, ra, 0, 1);
            rp[1] = __builtin_shufflevector(ra, ra, 2, 3);
            rp[2] = __builtin_shufflevector(rb, rb, 0, 1);
            rp[3] = __builtin_shufflevector(rb, rb, 2, 3);
            if (n == 0) {
                #pragma unroll
                for (int jp = 0; jp < 4; ++jp) {
                    PKMUL_L(acc2[0][jp], gp01, rp[jp]);
                    PKMUL_H(acc2[1][jp], gp01, rp[jp]);
                    PKMUL_L(acc2[2][jp], gp23, rp[jp]);
                    PKMUL_H(acc2[3][jp], gp23, rp[jp]);
                }
                acc8[0] = gp01.x * r8; acc8[1] = gp01.y * r8;
                acc8[2] = gp23.x * r8; acc8[3] = gp23.y * r8;
            } else {
                #pragma unroll
                for (int jp = 0; jp < 4; ++jp) {
                    PKFMA_L(acc2[0][jp], gp01, rp[jp]);
                    PKFMA_H(acc2[1][jp], gp01, rp[jp]);
                    PKFMA_L(acc2[2][jp], gp23, rp[jp]);
                    PKFMA_H(acc2[3][jp], gp23, rp[jp]);
                }
                acc8[0] += gp01.x * r8; acc8[1] += gp01.y * r8;
                acc8[2] += gp23.x * r8; acc8[3] += gp23.y * r8;
            }
        }
        #pragma unroll
        for (int ks = 0; ks < 9; ++ks) {
            frag[ks][2 * h]     = pkbf(ACC(0, ks), ACC(1, ks));
            frag[ks][2 * h + 1] = pkbf(ACC(2, ks), ACC(3, ks));
        }
    }

    // nz over all 32 channels of this lane's column (OR across coct groups)
    unsigned nzw = nzbits;
    nzw |= __shfl_xor(nzw, 16);
    nzw |= __shfl_xor(nzw, 32);

    // 7. MFMA: 9 K'-steps x 2 o-halves; A-operand from registers
    f32x4 c0 = {0.f, 0.f, 0.f, 0.f};
    f32x4 c1 = {0.f, 0.f, 0.f, 0.f};
    #pragma unroll
    for (int ks = 0; ks < 9; ++ks) {
        union { uint4 u; bf16x8 v; } bfr, au0, au1;
        bfr.u.x = frag[ks][0]; bfr.u.y = frag[ks][1];
        bfr.u.z = frag[ks][2]; bfr.u.w = frag[ks][3];
        au0.u = wa0[ks];
        au1.u = wa1[ks];
        c0 = __builtin_amdgcn_mfma_f32_16x16x32_bf16(au0.v, bfr.v, c0, 0, 0, 0);
        c1 = __builtin_amdgcn_mfma_f32_16x16x32_bf16(au1.v, bfr.v, c1, 0, 0, 0);
    }

    // 8. epilogue: col = vertex (16 consecutive -> 64B-coalesced per o-row)
    const int vglob = vt * 16 + arow;
    if (vglob < NV) {
        const float m = nzw ? 1.0f : 0.0f;
        float* ob = out + (size_t)bq * (COUT * NV) + vglob;
        #pragma unroll
        for (int r = 0; r < 4; ++r) {
            ob[(size_t)(coct * 4 + r) * NV]      = (c0[r] + bs0[r]) * m;
            ob[(size_t)(coct * 4 + 16 + r) * NV] = (c1[r] + bs1[r]) * m;
        }
    }
}

// ---------------------------------------------------------------------------
extern "C" void kernel_launch(void* const* d_in, const int* in_sizes, int n_in,
                              void* d_out, int out_size, void* d_ws, size_t ws_size,
                              hipStream_t stream)
{
    const float* x     = (const float*)d_in[0];
    const int*   index = (const int*)  d_in[1];
    const float* itp   = (const float*)d_in[2];
    const float* w     = (const float*)d_in[3];
    const float* bias  = (const float*)d_in[4];
    float*       out   = (float*)d_out;

    unsigned short* xt  = (unsigned short*)d_ws;                 // 10.5 MB
    unsigned short* wbf = (unsigned short*)((char*)d_ws + (size_t)NV * 256);

    const int vchunks = (NV + 63) / 64;      // 641 (>= 36 convert blocks)
    hipLaunchKernelGGL(transpose_x_bf16, dim3(vchunks), dim3(256), 0,
                       stream, x, (unsigned*)xt, w, wbf);
    hipLaunchKernelGGL(sparse_conv_mfma, dim3(4 * NBPB), dim3(256), 0,
                       stream, xt, index, itp, wbf, bias, out);
}